// Round 3
// baseline (824.058 us; speedup 1.0000x reference)
//
#include <hip/hip_runtime.h>

#define N_NODES 50000
#define DIM 128
#define N_EDGES 625000

typedef float f32x4 __attribute__((ext_vector_type(4)));
typedef short s16x8 __attribute__((ext_vector_type(8)));

union U8 { unsigned short us[8]; uint4 v; };

__device__ __forceinline__ float bf2f(unsigned short u) {
    unsigned v = ((unsigned)u) << 16;
    return __builtin_bit_cast(float, v);
}
__device__ __forceinline__ unsigned short f2bf(float f) {
    unsigned u = __builtin_bit_cast(unsigned, f);
    unsigned r = (u + 0x7fffu + ((u >> 16) & 1u)) >> 16;  // RNE
    return (unsigned short)r;
}

template <bool BF16>
__device__ __forceinline__ float ld1(const void* p, int i) {
    if (BF16) return bf2f(((const unsigned short*)p)[i]);
    return ((const float*)p)[i];
}
template <bool BF16>
__device__ __forceinline__ void ld2(const void* p, int i, float* o) {
    if (BF16) {
        unsigned pair = *(const unsigned*)((const unsigned short*)p + i);
        o[0] = bf2f((unsigned short)(pair & 0xffffu));
        o[1] = bf2f((unsigned short)(pair >> 16));
    } else {
        float2 f = *(const float2*)((const float*)p + i);
        o[0] = f.x; o[1] = f.y;
    }
}
template <bool BF16>
__device__ __forceinline__ void ld8(const void* p, int i, float* o) {
    if (BF16) {
        U8 u; u.v = *(const uint4*)((const unsigned short*)p + i);
        #pragma unroll
        for (int j = 0; j < 8; ++j) o[j] = bf2f(u.us[j]);
    } else {
        const float4* q = (const float4*)((const float*)p + i);
        float4 a = q[0], b = q[1];
        o[0] = a.x; o[1] = a.y; o[2] = a.z; o[3] = a.w;
        o[4] = b.x; o[5] = b.y; o[6] = b.z; o[7] = b.w;
    }
}

// ---- K_detect: flag=1 if float inputs are bf16, flag=0 if f32 ----
// For f32 data, even ushorts are mantissa-low bits (uniform) -> ~12.5% hit
// the plausible-bf16-exponent window; for bf16 data ~100% do.
__global__ void k_detect(const unsigned short* __restrict__ node, int* __restrict__ flag) {
    if (threadIdx.x == 0 && blockIdx.x == 0) {
        int cnt = 0;
        for (int i = 0; i < 128; ++i) {
            unsigned e = (node[2 * i] >> 7) & 0xFFu;
            if (e >= 96u && e < 128u) ++cnt;  // |x| in [2^-31, 2)
        }
        *flag = (cnt >= 64) ? 1 : 0;
    }
}

// ---- K0: pack W't[o][k] (o=out col 0..127, k=0..511) as bf16 ----
// k<128: lin_w[o][k] ; k=128+kk*128+i: conv_w[o][i][kk]
template <bool BF16>
__global__ void k_pack(const void* __restrict__ lin_w, const void* __restrict__ conv_w,
                       const int* __restrict__ flag, unsigned short* __restrict__ Wt) {
    if (*flag != (int)BF16) return;
    int idx = blockIdx.x * 256 + threadIdx.x;  // 65536 total
    int o = idx >> 9;
    int k = idx & 511;
    float v;
    if (k < 128) {
        v = ld1<BF16>(lin_w, o * 128 + k);
    } else {
        int kk = (k - 128) >> 7;
        int i = (k - 128) & 127;
        v = ld1<BF16>(conv_w, o * 384 + i * 3 + kk);
    }
    Wt[idx] = f2bf(v);
}

// ---- K1: per-row logmap0 scale for [node, h1, h2, h3] -> scales[4*N] ----
template <bool BF16>
__global__ void k_scales(const void* __restrict__ node, const void* __restrict__ h1,
                         const void* __restrict__ h2, const void* __restrict__ h3,
                         const void* __restrict__ curv, const int* __restrict__ flag,
                         float* __restrict__ scales) {
    if (*flag != (int)BF16) return;
    int row = blockIdx.x * 4 + (threadIdx.x >> 6);  // [0, 4N)
    int lane = threadIdx.x & 63;
    int a = row / N_NODES;
    int n = row - a * N_NODES;
    const void* src = (a == 0) ? node : (a == 1) ? h1 : (a == 2) ? h2 : h3;
    float x[2];
    ld2<BF16>(src, n * DIM + lane * 2, x);
    float ss = x[0] * x[0] + x[1] * x[1];
    #pragma unroll
    for (int m = 1; m < 64; m <<= 1) ss += __shfl_xor(ss, m, 64);
    float c = fabsf(ld1<BF16>(curv, 0));
    float sc = sqrtf(c);
    float xn = fmaxf(sqrtf(ss), 1e-15f);
    float arg = fminf(sc * xn, 1.0f - 1e-5f);
    float at = 0.5f * log1pf(2.0f * arg / (1.0f - arg));  // artanh
    if (lane == 0) scales[row] = at / (sc * xn);
}

// ---- K2: summed[dst] += node[src]*scale[src]; deg[dst]++ ----
template <bool BF16>
__global__ void k_scatter(const int* __restrict__ esrc, const int* __restrict__ edst,
                          const void* __restrict__ node, const float* __restrict__ node_scale,
                          const int* __restrict__ flag,
                          float* __restrict__ summed, int* __restrict__ deg) {
    if (*flag != (int)BF16) return;
    int e = blockIdx.x * 4 + (threadIdx.x >> 6);
    if (e >= N_EDGES) return;
    int lane = threadIdx.x & 63;
    int s = esrc[e];
    int d = edst[e];
    float sc = node_scale[s];
    float x[2];
    ld2<BF16>(node, s * DIM + lane * 2, x);
    float* dst = &summed[d * DIM + lane * 2];
    __hip_atomic_fetch_add(dst, x[0] * sc, __ATOMIC_RELAXED, __HIP_MEMORY_SCOPE_AGENT);
    __hip_atomic_fetch_add(dst + 1, x[1] * sc, __ATOMIC_RELAXED, __HIP_MEMORY_SCOPE_AGENT);
    if (lane == 0)
        __hip_atomic_fetch_add(&deg[d], 1, __ATOMIC_RELAXED, __HIP_MEMORY_SCOPE_AGENT);
}

// ---- K3: [N x 512] @ [512 x 128] bf16 MFMA GEMM + expmap0 epilogue (f32 out) ----
#define RB 64
template <bool BF16>
__global__ __launch_bounds__(256) void k_gemm(
    const float* __restrict__ summed, const int* __restrict__ deg,
    const float* __restrict__ scales,  // [4][N]
    const void* __restrict__ h1, const void* __restrict__ h2, const void* __restrict__ h3,
    const unsigned short* __restrict__ Wt,  // [128][512] bf16
    const void* __restrict__ lin_b, const void* __restrict__ conv_b,
    const void* __restrict__ curv, const int* __restrict__ flag,
    float* __restrict__ out) {
    if (*flag != (int)BF16) return;
    __shared__ __align__(16) unsigned short As[RB * 136];
    __shared__ __align__(16) unsigned short Bs[128 * 136];
    int tid = threadIdx.x;
    int n0 = blockIdx.x * RB;
    int w = tid >> 6;
    int lane = tid & 63;
    int ml = lane & 15;
    int q = lane >> 4;

    f32x4 acc[8];
    #pragma unroll
    for (int i = 0; i < 8; ++i) acc[i] = (f32x4){0.f, 0.f, 0.f, 0.f};

    for (int kk = 0; kk < 4; ++kk) {
        #pragma unroll
        for (int it = 0; it < 8; ++it) {
            int cch = it * 256 + tid;  // 2048 chunks of 8 bf16
            int o = cch >> 4;
            int kc = (cch & 15) * 8;
            *(uint4*)&Bs[o * 136 + kc] = *(const uint4*)&Wt[o * 512 + kk * 128 + kc];
        }
        if (kk == 0) {
            #pragma unroll
            for (int it = 0; it < 4; ++it) {
                int cch = it * 256 + tid;  // 1024 chunks of 8
                int r = cch >> 4;
                int ic = (cch & 15) * 8;
                int n = n0 + r;
                U8 u;
                if (n < N_NODES) {
                    int dg = deg[n];
                    float inv = dg > 0 ? 1.0f / (float)dg : 0.0f;
                    const float* sp = summed + n * DIM + ic;
                    float4 f0 = *(const float4*)sp;
                    float4 f1 = *(const float4*)(sp + 4);
                    u.us[0] = f2bf(f0.x * inv); u.us[1] = f2bf(f0.y * inv);
                    u.us[2] = f2bf(f0.z * inv); u.us[3] = f2bf(f0.w * inv);
                    u.us[4] = f2bf(f1.x * inv); u.us[5] = f2bf(f1.y * inv);
                    u.us[6] = f2bf(f1.z * inv); u.us[7] = f2bf(f1.w * inv);
                } else {
                    #pragma unroll
                    for (int j = 0; j < 8; ++j) u.us[j] = 0;
                }
                *(uint4*)&As[r * 136 + ic] = u.v;
            }
        } else {
            const void* hp = (kk == 1) ? h1 : (kk == 2) ? h2 : h3;
            const float* scl = scales + kk * N_NODES;
            #pragma unroll
            for (int it = 0; it < 4; ++it) {
                int cch = it * 256 + tid;
                int r = cch >> 4;
                int ic = (cch & 15) * 8;
                int n = n0 + r;
                U8 u;
                if (n < N_NODES) {
                    float s = scl[n];
                    float hv[8];
                    ld8<BF16>(hp, n * DIM + ic, hv);
                    #pragma unroll
                    for (int j = 0; j < 8; ++j) u.us[j] = f2bf(hv[j] * s);
                } else {
                    #pragma unroll
                    for (int j = 0; j < 8; ++j) u.us[j] = 0;
                }
                *(uint4*)&As[r * 136 + ic] = u.v;
            }
        }
        __syncthreads();
        #pragma unroll
        for (int ks = 0; ks < 4; ++ks) {
            s16x8 a = *(const s16x8*)&As[(w * 16 + ml) * 136 + ks * 32 + q * 8];
            #pragma unroll
            for (int ct = 0; ct < 8; ++ct) {
                s16x8 b = *(const s16x8*)&Bs[(ct * 16 + ml) * 136 + ks * 32 + q * 8];
                acc[ct] = __builtin_amdgcn_mfma_f32_16x16x32_bf16(a, b, acc[ct], 0, 0, 0);
            }
        }
        __syncthreads();
    }

    float c = fabsf(ld1<BF16>(curv, 0));
    float sc = sqrtf(c);
    float cb[8], lb[8];
    #pragma unroll
    for (int ct = 0; ct < 8; ++ct) {
        cb[ct] = ld1<BF16>(conv_b, ct * 16 + ml);
        lb[ct] = ld1<BF16>(lin_b, ct * 16 + ml);
    }
    #pragma unroll
    for (int r = 0; r < 4; ++r) {
        int n = n0 + w * 16 + q * 4 + r;  // D-frag: row = quad*4 + reg, col = lane&15
        bool valid = (n < N_NODES);
        float dgf = 0.f;
        if (valid) dgf = (deg[n] > 0) ? 1.0f : 0.0f;
        float y[8];
        float ssq = 0.f;
        #pragma unroll
        for (int ct = 0; ct < 8; ++ct) {
            float v = acc[ct][r] + cb[ct] + dgf * lb[ct];
            y[ct] = v;
            ssq += v * v;
        }
        ssq += __shfl_xor(ssq, 1, 64);
        ssq += __shfl_xor(ssq, 2, 64);
        ssq += __shfl_xor(ssq, 4, 64);
        ssq += __shfl_xor(ssq, 8, 64);
        float un = fmaxf(sqrtf(ssq), 1e-15f);
        float os = tanhf(sc * un) / (sc * un);
        if (valid) {
            #pragma unroll
            for (int ct = 0; ct < 8; ++ct)
                out[n * DIM + ct * 16 + ml] = y[ct] * os;  // f32 output
        }
    }
}

extern "C" void kernel_launch(void* const* d_in, const int* in_sizes, int n_in,
                              void* d_out, int out_size, void* d_ws, size_t ws_size,
                              hipStream_t stream) {
    (void)in_sizes; (void)n_in; (void)out_size; (void)ws_size;
    const void* node   = d_in[0];
    const void* h1     = d_in[1];
    const void* h2     = d_in[2];
    const void* h3     = d_in[3];
    const void* lin_w  = d_in[4];
    const void* lin_b  = d_in[5];
    const void* conv_w = d_in[6];
    const void* conv_b = d_in[7];
    const void* curv   = d_in[8];
    const int* esrc = (const int*)d_in[9];
    const int* edst = (const int*)d_in[10];
    float* out = (float*)d_out;  // OUTPUT IS FLOAT32 (threshold = max|ref|/50 w/ f32 ref)

    // ws layout (bytes):
    //   [0, 25,600,000)           summed f32 [N][128]
    //   [25,600,000, 25,800,000)  deg    i32 [N]
    //   [25,800,000, 26,600,000)  scales f32 [4][N]
    //   [26,600,000, 26,731,072)  Wt     bf16 [128][512]
    //   [26,731,072, +4)          dtype flag
    char* ws = (char*)d_ws;
    float* summed = (float*)ws;
    int* deg = (int*)(ws + 25600000);
    float* scales = (float*)(ws + 25800000);
    unsigned short* Wt = (unsigned short*)(ws + 26600000);
    int* flag = (int*)(ws + 26731072);

    hipMemsetAsync(d_ws, 0, 25800000, stream);  // zero summed + deg
    hipLaunchKernelGGL(k_detect, dim3(1), dim3(64), 0, stream,
                       (const unsigned short*)node, flag);
    hipLaunchKernelGGL(k_pack<false>, dim3(256), dim3(256), 0, stream, lin_w, conv_w, flag, Wt);
    hipLaunchKernelGGL(k_pack<true>,  dim3(256), dim3(256), 0, stream, lin_w, conv_w, flag, Wt);
    hipLaunchKernelGGL(k_scales<false>, dim3(50000), dim3(256), 0, stream,
                       node, h1, h2, h3, curv, flag, scales);
    hipLaunchKernelGGL(k_scales<true>,  dim3(50000), dim3(256), 0, stream,
                       node, h1, h2, h3, curv, flag, scales);
    hipLaunchKernelGGL(k_scatter<false>, dim3(156250), dim3(256), 0, stream,
                       esrc, edst, node, scales, flag, summed, deg);
    hipLaunchKernelGGL(k_scatter<true>,  dim3(156250), dim3(256), 0, stream,
                       esrc, edst, node, scales, flag, summed, deg);
    hipLaunchKernelGGL(k_gemm<false>, dim3((N_NODES + RB - 1) / RB), dim3(256), 0, stream,
                       summed, deg, scales, h1, h2, h3, Wt, lin_b, conv_b, curv, flag, out);
    hipLaunchKernelGGL(k_gemm<true>,  dim3((N_NODES + RB - 1) / RB), dim3(256), 0, stream,
                       summed, deg, scales, h1, h2, h3, Wt, lin_b, conv_b, curv, flag, out);
}

// Round 5
// 345.731 us; speedup vs baseline: 2.3835x; 2.3835x over previous
//
#include <hip/hip_runtime.h>

#define N_NODES 50000
#define DIM 128
#define N_EDGES 625000
#define NBLK 196   // ceil(N/256) scan blocks
#define EBLK 2442  // ceil(E/256) edge blocks

typedef float f32x4 __attribute__((ext_vector_type(4)));
typedef short s16x8 __attribute__((ext_vector_type(8)));

union U8 { unsigned short us[8]; uint4 v; };

__device__ __forceinline__ float bf2f(unsigned short u) {
    unsigned v = ((unsigned)u) << 16;
    return __builtin_bit_cast(float, v);
}
__device__ __forceinline__ unsigned short f2bf(float f) {
    unsigned u = __builtin_bit_cast(unsigned, f);
    unsigned r = (u + 0x7fffu + ((u >> 16) & 1u)) >> 16;  // RNE
    return (unsigned short)r;
}

// ---- K0: pack W't[o][k] (o=out col, k=0..511) as bf16 ----
// k<128: lin_w[o][k] ; k=128+kk*128+i: conv_w[o][i][kk]
__global__ void k_pack(const float* __restrict__ lin_w, const float* __restrict__ conv_w,
                       unsigned short* __restrict__ Wt) {
    int idx = blockIdx.x * 256 + threadIdx.x;  // 65536
    int o = idx >> 9;
    int k = idx & 511;
    float v;
    if (k < 128) {
        v = lin_w[o * 128 + k];
    } else {
        int kk = (k - 128) >> 7;
        int i = (k - 128) & 127;
        v = conv_w[o * 384 + i * 3 + kk];
    }
    Wt[idx] = f2bf(v);
}

// ---- K1: per-row logmap0 scale for [node, h1, h2, h3] -> scales[4*N] ----
__global__ void k_scales(const float* __restrict__ node, const float* __restrict__ h1,
                         const float* __restrict__ h2, const float* __restrict__ h3,
                         const float* __restrict__ curv, float* __restrict__ scales) {
    int row = blockIdx.x * 4 + (threadIdx.x >> 6);  // [0, 4N)
    int lane = threadIdx.x & 63;
    int a = row / N_NODES;
    int n = row - a * N_NODES;
    const float* src = (a == 0) ? node : (a == 1) ? h1 : (a == 2) ? h2 : h3;
    float2 x = *(const float2*)&src[n * DIM + lane * 2];
    float ss = x.x * x.x + x.y * x.y;
    #pragma unroll
    for (int m = 1; m < 64; m <<= 1) ss += __shfl_xor(ss, m, 64);
    float c = fabsf(curv[0]);
    float sc = sqrtf(c);
    float xn = fmaxf(sqrtf(ss), 1e-15f);
    float arg = fminf(sc * xn, 1.0f - 1e-5f);
    float at = 0.5f * log1pf(2.0f * arg / (1.0f - arg));  // artanh
    if (lane == 0) scales[row] = at / (sc * xn);
}

// ---- K2: degree histogram ----
__global__ void k_hist(const int* __restrict__ edst, int* __restrict__ deg) {
    int e = blockIdx.x * 256 + threadIdx.x;
    if (e < N_EDGES)
        __hip_atomic_fetch_add(&deg[edst[e]], 1, __ATOMIC_RELAXED, __HIP_MEMORY_SCOPE_AGENT);
}

// ---- K3a: per-256-chunk exclusive scan; chunk totals -> blocksum ----
__global__ void k_scan1(const int* __restrict__ deg, int* __restrict__ rowstart,
                        int* __restrict__ blocksum) {
    __shared__ int sm[256];
    int t = threadIdx.x;
    int i = blockIdx.x * 256 + t;
    int v = (i < N_NODES) ? deg[i] : 0;
    sm[t] = v;
    __syncthreads();
    #pragma unroll
    for (int off = 1; off < 256; off <<= 1) {
        int x = (t >= off) ? sm[t - off] : 0;
        __syncthreads();
        sm[t] += x;
        __syncthreads();
    }
    if (i < N_NODES) rowstart[i] = sm[t] - v;  // exclusive within chunk
    if (t == 255) blocksum[blockIdx.x] = sm[t];
}

// ---- K3b: exclusive scan of the 196 chunk totals (in place) ----
__global__ void k_scan2(int* __restrict__ blocksum) {
    __shared__ int sm[256];
    int t = threadIdx.x;
    int v = (t < NBLK) ? blocksum[t] : 0;
    sm[t] = v;
    __syncthreads();
    #pragma unroll
    for (int off = 1; off < 256; off <<= 1) {
        int x = (t >= off) ? sm[t - off] : 0;
        __syncthreads();
        sm[t] += x;
        __syncthreads();
    }
    if (t < NBLK) blocksum[t] = sm[t] - v;  // exclusive
}

// ---- K4: bucket edge sources by destination (CSR fill) ----
// row n start = rowstart[n] + blocksum[n>>8]
__global__ void k_bucket(const int* __restrict__ esrc, const int* __restrict__ edst,
                         const int* __restrict__ rowstart, const int* __restrict__ blocksum,
                         int* __restrict__ cursor, int* __restrict__ csr_src) {
    int e = blockIdx.x * 256 + threadIdx.x;
    if (e >= N_EDGES) return;
    int d = edst[e];
    int pos = __hip_atomic_fetch_add(&cursor[d], 1, __ATOMIC_RELAXED, __HIP_MEMORY_SCOPE_AGENT);
    csr_src[rowstart[d] + blocksum[d >> 8] + pos] = esrc[e];
}

// ---- K5: gather: neigh[n] = bf16( (1/deg) * sum_{s in row n} node[s]*scale[s] ) ----
__global__ __launch_bounds__(256) void k_gather(
    const int* __restrict__ csr_src, const int* __restrict__ rowstart,
    const int* __restrict__ blocksum, const int* __restrict__ deg,
    const float* __restrict__ node, const float* __restrict__ scales,
    unsigned short* __restrict__ neigh) {
    int n = blockIdx.x * 4 + (threadIdx.x >> 6);
    int lane = threadIdx.x & 63;
    int begin = rowstart[n] + blocksum[n >> 8];
    int cnt = deg[n];
    float a0 = 0.f, a1 = 0.f;
    for (int base = 0; base < cnt; base += 64) {
        int rem = cnt - base;
        int m = rem < 64 ? rem : 64;
        int my = (lane < m) ? csr_src[begin + base + lane] : 0;
        float mysc = (lane < m) ? scales[my] : 0.f;
        for (int i = 0; i < m; ++i) {
            int s = __shfl(my, i, 64);
            float sc = __shfl(mysc, i, 64);
            float2 v = *(const float2*)&node[s * DIM + lane * 2];
            a0 += v.x * sc;
            a1 += v.y * sc;
        }
    }
    float inv = (cnt > 0) ? 1.0f / (float)cnt : 0.0f;
    unsigned short b0 = f2bf(a0 * inv), b1 = f2bf(a1 * inv);
    *(unsigned*)&neigh[n * DIM + lane * 2] = (unsigned)b0 | ((unsigned)b1 << 16);
}

// ---- K6: [N x 512] @ [512 x 128] bf16 MFMA GEMM + expmap0 epilogue (f32 out) ----
#define RB 64
__global__ __launch_bounds__(256) void k_gemm(
    const unsigned short* __restrict__ neigh, const int* __restrict__ deg,
    const float* __restrict__ scales,  // [4][N]; rows 1..3 are hist scales
    const float* __restrict__ h1, const float* __restrict__ h2, const float* __restrict__ h3,
    const unsigned short* __restrict__ Wt,  // [128][512] bf16
    const float* __restrict__ lin_b, const float* __restrict__ conv_b,
    const float* __restrict__ curv, float* __restrict__ out) {
    __shared__ __align__(16) unsigned short As[RB * 136];
    __shared__ __align__(16) unsigned short Bs[128 * 136];
    int tid = threadIdx.x;
    int n0 = blockIdx.x * RB;
    int w = tid >> 6;
    int lane = tid & 63;
    int ml = lane & 15;
    int q = lane >> 4;

    f32x4 acc[8];
    #pragma unroll
    for (int i = 0; i < 8; ++i) acc[i] = (f32x4){0.f, 0.f, 0.f, 0.f};

    for (int kk = 0; kk < 4; ++kk) {
        #pragma unroll
        for (int it = 0; it < 8; ++it) {
            int cch = it * 256 + tid;  // 2048 chunks of 8 bf16
            int o = cch >> 4;
            int kc = (cch & 15) * 8;
            *(uint4*)&Bs[o * 136 + kc] = *(const uint4*)&Wt[o * 512 + kk * 128 + kc];
        }
        if (kk == 0) {
            #pragma unroll
            for (int it = 0; it < 4; ++it) {
                int cch = it * 256 + tid;  // 1024 chunks of 8
                int r = cch >> 4;
                int ic = (cch & 15) * 8;
                int n = n0 + r;
                U8 u;
                if (n < N_NODES) {
                    u.v = *(const uint4*)&neigh[n * DIM + ic];
                } else {
                    #pragma unroll
                    for (int j = 0; j < 8; ++j) u.us[j] = 0;
                }
                *(uint4*)&As[r * 136 + ic] = u.v;
            }
        } else {
            const float* hp = (kk == 1) ? h1 : (kk == 2) ? h2 : h3;
            const float* scl = scales + kk * N_NODES;
            #pragma unroll
            for (int it = 0; it < 4; ++it) {
                int cch = it * 256 + tid;
                int r = cch >> 4;
                int ic = (cch & 15) * 8;
                int n = n0 + r;
                U8 u;
                if (n < N_NODES) {
                    float s = scl[n];
                    const float4* fp = (const float4*)&hp[n * DIM + ic];
                    float4 f0 = fp[0], f1 = fp[1];
                    u.us[0] = f2bf(f0.x * s); u.us[1] = f2bf(f0.y * s);
                    u.us[2] = f2bf(f0.z * s); u.us[3] = f2bf(f0.w * s);
                    u.us[4] = f2bf(f1.x * s); u.us[5] = f2bf(f1.y * s);
                    u.us[6] = f2bf(f1.z * s); u.us[7] = f2bf(f1.w * s);
                } else {
                    #pragma unroll
                    for (int j = 0; j < 8; ++j) u.us[j] = 0;
                }
                *(uint4*)&As[r * 136 + ic] = u.v;
            }
        }
        __syncthreads();
        #pragma unroll
        for (int ks = 0; ks < 4; ++ks) {
            s16x8 a = *(const s16x8*)&As[(w * 16 + ml) * 136 + ks * 32 + q * 8];
            #pragma unroll
            for (int ct = 0; ct < 8; ++ct) {
                s16x8 b = *(const s16x8*)&Bs[(ct * 16 + ml) * 136 + ks * 32 + q * 8];
                acc[ct] = __builtin_amdgcn_mfma_f32_16x16x32_bf16(a, b, acc[ct], 0, 0, 0);
            }
        }
        __syncthreads();
    }

    float c = fabsf(curv[0]);
    float sc = sqrtf(c);
    float cb[8], lb[8];
    #pragma unroll
    for (int ct = 0; ct < 8; ++ct) {
        cb[ct] = conv_b[ct * 16 + ml];
        lb[ct] = lin_b[ct * 16 + ml];
    }
    #pragma unroll
    for (int r = 0; r < 4; ++r) {
        int n = n0 + w * 16 + q * 4 + r;  // D-frag: row = quad*4 + reg, col = lane&15
        bool valid = (n < N_NODES);
        float dgf = 0.f;
        if (valid) dgf = (deg[n] > 0) ? 1.0f : 0.0f;
        float y[8];
        float ssq = 0.f;
        #pragma unroll
        for (int ct = 0; ct < 8; ++ct) {
            float v = acc[ct][r] + cb[ct] + dgf * lb[ct];
            y[ct] = v;
            ssq += v * v;
        }
        ssq += __shfl_xor(ssq, 1, 64);
        ssq += __shfl_xor(ssq, 2, 64);
        ssq += __shfl_xor(ssq, 4, 64);
        ssq += __shfl_xor(ssq, 8, 64);
        float un = fmaxf(sqrtf(ssq), 1e-15f);
        float os = tanhf(sc * un) / (sc * un);
        if (valid) {
            #pragma unroll
            for (int ct = 0; ct < 8; ++ct)
                out[n * DIM + ct * 16 + ml] = y[ct] * os;  // f32 output
        }
    }
}

extern "C" void kernel_launch(void* const* d_in, const int* in_sizes, int n_in,
                              void* d_out, int out_size, void* d_ws, size_t ws_size,
                              hipStream_t stream) {
    (void)in_sizes; (void)n_in; (void)out_size; (void)ws_size;
    const float* node   = (const float*)d_in[0];   // inputs are f32 (confirmed R3)
    const float* h1     = (const float*)d_in[1];
    const float* h2     = (const float*)d_in[2];
    const float* h3     = (const float*)d_in[3];
    const float* lin_w  = (const float*)d_in[4];
    const float* lin_b  = (const float*)d_in[5];
    const float* conv_w = (const float*)d_in[6];
    const float* conv_b = (const float*)d_in[7];
    const float* curv   = (const float*)d_in[8];
    const int* esrc = (const int*)d_in[9];
    const int* edst = (const int*)d_in[10];
    float* out = (float*)d_out;  // output is f32 (confirmed R3)

    // ws layout (bytes):
    //   [0, 12,800,000)           neigh    bf16 [N][128]
    //   [12,800,000, 13,600,000)  scales   f32  [4][N]
    //   [13,600,000, 13,731,072)  Wt       bf16 [128][512]
    //   [13,731,072, 13,931,072)  deg      i32  [N]
    //   [13,931,072, 14,131,072)  cursor   i32  [N]
    //   [14,131,072, 14,331,072)  rowstart i32  [N]
    //   [14,331,072, 16,831,072)  csr_src  i32  [E]
    //   [16,831,072, 16,832,096)  blocksum i32  [256]
    char* ws = (char*)d_ws;
    unsigned short* neigh = (unsigned short*)ws;
    float* scales = (float*)(ws + 12800000);
    unsigned short* Wt = (unsigned short*)(ws + 13600000);
    int* deg = (int*)(ws + 13731072);
    int* cursor = (int*)(ws + 13931072);
    int* rowstart = (int*)(ws + 14131072);
    int* csr_src = (int*)(ws + 14331072);
    int* blocksum = (int*)(ws + 16831072);

    (void)hipMemsetAsync(deg, 0, 400000, stream);  // zero deg + cursor
    hipLaunchKernelGGL(k_pack, dim3(256), dim3(256), 0, stream, lin_w, conv_w, Wt);
    hipLaunchKernelGGL(k_scales, dim3(50000), dim3(256), 0, stream,
                       node, h1, h2, h3, curv, scales);
    hipLaunchKernelGGL(k_hist, dim3(EBLK), dim3(256), 0, stream, edst, deg);
    hipLaunchKernelGGL(k_scan1, dim3(NBLK), dim3(256), 0, stream, deg, rowstart, blocksum);
    hipLaunchKernelGGL(k_scan2, dim3(1), dim3(256), 0, stream, blocksum);
    hipLaunchKernelGGL(k_bucket, dim3(EBLK), dim3(256), 0, stream,
                       esrc, edst, rowstart, blocksum, cursor, csr_src);
    hipLaunchKernelGGL(k_gather, dim3(12500), dim3(256), 0, stream,
                       csr_src, rowstart, blocksum, deg, node, scales, neigh);
    hipLaunchKernelGGL(k_gemm, dim3((N_NODES + RB - 1) / RB), dim3(256), 0, stream,
                       neigh, deg, scales, h1, h2, h3, Wt, lin_b, conv_b, curv, out);
}

// Round 6
// 295.958 us; speedup vs baseline: 2.7844x; 1.1682x over previous
//
#include <hip/hip_runtime.h>

#define N_NODES 50000
#define DIM 128
#define N_EDGES 625000
#define NBLK 196   // ceil(N/256) scan blocks
#define EBLK 2442  // ceil(E/256) edge blocks

typedef float f32x4 __attribute__((ext_vector_type(4)));
typedef short s16x8 __attribute__((ext_vector_type(8)));

union U8 { unsigned short us[8]; uint4 v; };

__device__ __forceinline__ float bf2f(unsigned short u) {
    unsigned v = ((unsigned)u) << 16;
    return __builtin_bit_cast(float, v);
}
__device__ __forceinline__ unsigned short f2bf(float f) {
    unsigned u = __builtin_bit_cast(unsigned, f);
    unsigned r = (u + 0x7fffu + ((u >> 16) & 1u)) >> 16;  // RNE
    return (unsigned short)r;
}

// ---- K0: pack W't[o][k] (o=out col, k=0..511) as bf16 ----
// k<128: lin_w[o][k] ; k=128+kk*128+i: conv_w[o][i][kk]
__global__ void k_pack(const float* __restrict__ lin_w, const float* __restrict__ conv_w,
                       unsigned short* __restrict__ Wt) {
    int idx = blockIdx.x * 256 + threadIdx.x;  // 65536
    int o = idx >> 9;
    int k = idx & 511;
    float v;
    if (k < 128) {
        v = lin_w[o * 128 + k];
    } else {
        int kk = (k - 128) >> 7;
        int i = (k - 128) & 127;
        v = conv_w[o * 384 + i * 3 + kk];
    }
    Wt[idx] = f2bf(v);
}

// ---- K1: per-row logmap0 scale for [node, h1, h2, h3] -> scales[4*N] ----
// 16 lanes per row (2x float4 each), 4 rows per wave, 16 rows per block.
__global__ __launch_bounds__(256) void k_scales(
    const float* __restrict__ node, const float* __restrict__ h1,
    const float* __restrict__ h2, const float* __restrict__ h3,
    const float* __restrict__ curv, float* __restrict__ scales) {
    int tid = threadIdx.x;
    int row = blockIdx.x * 16 + (tid >> 4);  // [0, 4N), 12500 blocks
    int g = tid & 15;
    int a = row / N_NODES;
    int n = row - a * N_NODES;
    const float* src = (a == 0) ? node : (a == 1) ? h1 : (a == 2) ? h2 : h3;
    const float4* p = (const float4*)&src[n * DIM + g * 8];
    float4 x0 = p[0], x1 = p[1];
    float ss = x0.x * x0.x + x0.y * x0.y + x0.z * x0.z + x0.w * x0.w
             + x1.x * x1.x + x1.y * x1.y + x1.z * x1.z + x1.w * x1.w;
    ss += __shfl_xor(ss, 1, 64);
    ss += __shfl_xor(ss, 2, 64);
    ss += __shfl_xor(ss, 4, 64);
    ss += __shfl_xor(ss, 8, 64);  // reduces within the 16-lane group
    float c = fabsf(curv[0]);
    float sc = sqrtf(c);
    float xn = fmaxf(sqrtf(ss), 1e-15f);
    float arg = fminf(sc * xn, 1.0f - 1e-5f);
    float at = 0.5f * log1pf(2.0f * arg / (1.0f - arg));  // artanh
    if (g == 0) scales[row] = at / (sc * xn);
}

// ---- K2: degree histogram ----
__global__ void k_hist(const int* __restrict__ edst, int* __restrict__ deg) {
    int e = blockIdx.x * 256 + threadIdx.x;
    if (e < N_EDGES)
        __hip_atomic_fetch_add(&deg[edst[e]], 1, __ATOMIC_RELAXED, __HIP_MEMORY_SCOPE_AGENT);
}

// ---- K3a: per-256-chunk exclusive scan; chunk totals -> blocksum ----
__global__ void k_scan1(const int* __restrict__ deg, int* __restrict__ rowstart,
                        int* __restrict__ blocksum) {
    __shared__ int sm[256];
    int t = threadIdx.x;
    int i = blockIdx.x * 256 + t;
    int v = (i < N_NODES) ? deg[i] : 0;
    sm[t] = v;
    __syncthreads();
    #pragma unroll
    for (int off = 1; off < 256; off <<= 1) {
        int x = (t >= off) ? sm[t - off] : 0;
        __syncthreads();
        sm[t] += x;
        __syncthreads();
    }
    if (i < N_NODES) rowstart[i] = sm[t] - v;  // exclusive within chunk
    if (t == 255) blocksum[blockIdx.x] = sm[t];
}

// ---- K3b: exclusive scan of the 196 chunk totals (in place) ----
__global__ void k_scan2(int* __restrict__ blocksum) {
    __shared__ int sm[256];
    int t = threadIdx.x;
    int v = (t < NBLK) ? blocksum[t] : 0;
    sm[t] = v;
    __syncthreads();
    #pragma unroll
    for (int off = 1; off < 256; off <<= 1) {
        int x = (t >= off) ? sm[t - off] : 0;
        __syncthreads();
        sm[t] += x;
        __syncthreads();
    }
    if (t < NBLK) blocksum[t] = sm[t] - v;  // exclusive
}

// ---- K4: bucket edge sources by destination (CSR fill) ----
__global__ void k_bucket(const int* __restrict__ esrc, const int* __restrict__ edst,
                         const int* __restrict__ rowstart, const int* __restrict__ blocksum,
                         int* __restrict__ cursor, int* __restrict__ csr_src) {
    int e = blockIdx.x * 256 + threadIdx.x;
    if (e >= N_EDGES) return;
    int d = edst[e];
    int pos = __hip_atomic_fetch_add(&cursor[d], 1, __ATOMIC_RELAXED, __HIP_MEMORY_SCOPE_AGENT);
    csr_src[rowstart[d] + blocksum[d >> 8] + pos] = esrc[e];
}

// ---- K5: gather: neigh[n] = bf16( (1/deg) * sum_{s in row n} node[s]*scale[s] ) ----
// One wave per row; 4-way unrolled inner loop (4 independent row loads in flight).
__global__ __launch_bounds__(256) void k_gather(
    const int* __restrict__ csr_src, const int* __restrict__ rowstart,
    const int* __restrict__ blocksum, const int* __restrict__ deg,
    const float* __restrict__ node, const float* __restrict__ scales,
    unsigned short* __restrict__ neigh) {
    int n = blockIdx.x * 4 + (threadIdx.x >> 6);
    int lane = threadIdx.x & 63;
    int begin = rowstart[n] + blocksum[n >> 8];
    int cnt = deg[n];
    float a0 = 0.f, a1 = 0.f, b0 = 0.f, b1 = 0.f;
    float c0 = 0.f, c1 = 0.f, d0 = 0.f, d1 = 0.f;
    for (int base = 0; base < cnt; base += 64) {
        int rem = cnt - base;
        int m = rem < 64 ? rem : 64;
        int my = (lane < m) ? csr_src[begin + base + lane] : 0;
        float mysc = (lane < m) ? scales[my] : 0.f;
        int i = 0;
        for (; i + 4 <= m; i += 4) {
            int s0 = __shfl(my, i, 64),     s1 = __shfl(my, i + 1, 64);
            int s2 = __shfl(my, i + 2, 64), s3 = __shfl(my, i + 3, 64);
            float f0 = __shfl(mysc, i, 64),     f1 = __shfl(mysc, i + 1, 64);
            float f2 = __shfl(mysc, i + 2, 64), f3 = __shfl(mysc, i + 3, 64);
            float2 v0 = *(const float2*)&node[s0 * DIM + lane * 2];
            float2 v1 = *(const float2*)&node[s1 * DIM + lane * 2];
            float2 v2 = *(const float2*)&node[s2 * DIM + lane * 2];
            float2 v3 = *(const float2*)&node[s3 * DIM + lane * 2];
            a0 += v0.x * f0; a1 += v0.y * f0;
            b0 += v1.x * f1; b1 += v1.y * f1;
            c0 += v2.x * f2; c1 += v2.y * f2;
            d0 += v3.x * f3; d1 += v3.y * f3;
        }
        for (; i < m; ++i) {
            int s = __shfl(my, i, 64);
            float sc = __shfl(mysc, i, 64);
            float2 v = *(const float2*)&node[s * DIM + lane * 2];
            a0 += v.x * sc; a1 += v.y * sc;
        }
    }
    float t0 = (a0 + b0) + (c0 + d0);
    float t1 = (a1 + b1) + (c1 + d1);
    float inv = (cnt > 0) ? 1.0f / (float)cnt : 0.0f;
    unsigned short o0 = f2bf(t0 * inv), o1 = f2bf(t1 * inv);
    *(unsigned*)&neigh[n * DIM + lane * 2] = (unsigned)o0 | ((unsigned)o1 << 16);
}

// ---- K6: [N x 512] @ [512 x 128] bf16 MFMA GEMM + expmap0 epilogue (f32 out) ----
#define RB 64
__global__ __launch_bounds__(256) void k_gemm(
    const unsigned short* __restrict__ neigh, const int* __restrict__ deg,
    const float* __restrict__ scales,  // [4][N]; rows 1..3 are hist scales
    const float* __restrict__ h1, const float* __restrict__ h2, const float* __restrict__ h3,
    const unsigned short* __restrict__ Wt,  // [128][512] bf16
    const float* __restrict__ lin_b, const float* __restrict__ conv_b,
    const float* __restrict__ curv, float* __restrict__ out) {
    __shared__ __align__(16) unsigned short As[RB * 136];
    __shared__ __align__(16) unsigned short Bs[128 * 136];
    int tid = threadIdx.x;
    int n0 = blockIdx.x * RB;
    int w = tid >> 6;
    int lane = tid & 63;
    int ml = lane & 15;
    int q = lane >> 4;

    f32x4 acc[8];
    #pragma unroll
    for (int i = 0; i < 8; ++i) acc[i] = (f32x4){0.f, 0.f, 0.f, 0.f};

    for (int kk = 0; kk < 4; ++kk) {
        #pragma unroll
        for (int it = 0; it < 8; ++it) {
            int cch = it * 256 + tid;  // 2048 chunks of 8 bf16
            int o = cch >> 4;
            int kc = (cch & 15) * 8;
            *(uint4*)&Bs[o * 136 + kc] = *(const uint4*)&Wt[o * 512 + kk * 128 + kc];
        }
        if (kk == 0) {
            #pragma unroll
            for (int it = 0; it < 4; ++it) {
                int cch = it * 256 + tid;  // 1024 chunks of 8
                int r = cch >> 4;
                int ic = (cch & 15) * 8;
                int n = n0 + r;
                U8 u;
                if (n < N_NODES) {
                    u.v = *(const uint4*)&neigh[n * DIM + ic];
                } else {
                    #pragma unroll
                    for (int j = 0; j < 8; ++j) u.us[j] = 0;
                }
                *(uint4*)&As[r * 136 + ic] = u.v;
            }
        } else {
            const float* hp = (kk == 1) ? h1 : (kk == 2) ? h2 : h3;
            const float* scl = scales + kk * N_NODES;
            #pragma unroll
            for (int it = 0; it < 4; ++it) {
                int cch = it * 256 + tid;
                int r = cch >> 4;
                int ic = (cch & 15) * 8;
                int n = n0 + r;
                U8 u;
                if (n < N_NODES) {
                    float s = scl[n];
                    const float4* fp = (const float4*)&hp[n * DIM + ic];
                    float4 f0 = fp[0], f1 = fp[1];
                    u.us[0] = f2bf(f0.x * s); u.us[1] = f2bf(f0.y * s);
                    u.us[2] = f2bf(f0.z * s); u.us[3] = f2bf(f0.w * s);
                    u.us[4] = f2bf(f1.x * s); u.us[5] = f2bf(f1.y * s);
                    u.us[6] = f2bf(f1.z * s); u.us[7] = f2bf(f1.w * s);
                } else {
                    #pragma unroll
                    for (int j = 0; j < 8; ++j) u.us[j] = 0;
                }
                *(uint4*)&As[r * 136 + ic] = u.v;
            }
        }
        __syncthreads();
        #pragma unroll
        for (int ks = 0; ks < 4; ++ks) {
            s16x8 a = *(const s16x8*)&As[(w * 16 + ml) * 136 + ks * 32 + q * 8];
            #pragma unroll
            for (int ct = 0; ct < 8; ++ct) {
                s16x8 b = *(const s16x8*)&Bs[(ct * 16 + ml) * 136 + ks * 32 + q * 8];
                acc[ct] = __builtin_amdgcn_mfma_f32_16x16x32_bf16(a, b, acc[ct], 0, 0, 0);
            }
        }
        __syncthreads();
    }

    float c = fabsf(curv[0]);
    float sc = sqrtf(c);
    float cb[8], lb[8];
    #pragma unroll
    for (int ct = 0; ct < 8; ++ct) {
        cb[ct] = conv_b[ct * 16 + ml];
        lb[ct] = lin_b[ct * 16 + ml];
    }
    #pragma unroll
    for (int r = 0; r < 4; ++r) {
        int n = n0 + w * 16 + q * 4 + r;  // D-frag: row = quad*4 + reg, col = lane&15
        bool valid = (n < N_NODES);
        float dgf = 0.f;
        if (valid) dgf = (deg[n] > 0) ? 1.0f : 0.0f;
        float y[8];
        float ssq = 0.f;
        #pragma unroll
        for (int ct = 0; ct < 8; ++ct) {
            float v = acc[ct][r] + cb[ct] + dgf * lb[ct];
            y[ct] = v;
            ssq += v * v;
        }
        ssq += __shfl_xor(ssq, 1, 64);
        ssq += __shfl_xor(ssq, 2, 64);
        ssq += __shfl_xor(ssq, 4, 64);
        ssq += __shfl_xor(ssq, 8, 64);
        float un = fmaxf(sqrtf(ssq), 1e-15f);
        float os = tanhf(sc * un) / (sc * un);
        if (valid) {
            #pragma unroll
            for (int ct = 0; ct < 8; ++ct)
                out[n * DIM + ct * 16 + ml] = y[ct] * os;  // f32 output
        }
    }
}

extern "C" void kernel_launch(void* const* d_in, const int* in_sizes, int n_in,
                              void* d_out, int out_size, void* d_ws, size_t ws_size,
                              hipStream_t stream) {
    (void)in_sizes; (void)n_in; (void)out_size; (void)ws_size;
    const float* node   = (const float*)d_in[0];   // inputs f32, output f32 (confirmed R3)
    const float* h1     = (const float*)d_in[1];
    const float* h2     = (const float*)d_in[2];
    const float* h3     = (const float*)d_in[3];
    const float* lin_w  = (const float*)d_in[4];
    const float* lin_b  = (const float*)d_in[5];
    const float* conv_w = (const float*)d_in[6];
    const float* conv_b = (const float*)d_in[7];
    const float* curv   = (const float*)d_in[8];
    const int* esrc = (const int*)d_in[9];
    const int* edst = (const int*)d_in[10];
    float* out = (float*)d_out;

    // ws layout (bytes):
    //   [0, 12,800,000)           neigh    bf16 [N][128]
    //   [12,800,000, 13,600,000)  scales   f32  [4][N]
    //   [13,600,000, 13,731,072)  Wt       bf16 [128][512]
    //   [13,731,072, 13,931,072)  deg      i32  [N]
    //   [13,931,072, 14,131,072)  cursor   i32  [N]
    //   [14,131,072, 14,331,072)  rowstart i32  [N]
    //   [14,331,072, 16,831,072)  csr_src  i32  [E]
    //   [16,831,072, 16,832,096)  blocksum i32  [256]
    char* ws = (char*)d_ws;
    unsigned short* neigh = (unsigned short*)ws;
    float* scales = (float*)(ws + 12800000);
    unsigned short* Wt = (unsigned short*)(ws + 13600000);
    int* deg = (int*)(ws + 13731072);
    int* cursor = (int*)(ws + 13931072);
    int* rowstart = (int*)(ws + 14131072);
    int* csr_src = (int*)(ws + 14331072);
    int* blocksum = (int*)(ws + 16831072);

    (void)hipMemsetAsync(deg, 0, 400000, stream);  // zero deg + cursor
    hipLaunchKernelGGL(k_pack, dim3(256), dim3(256), 0, stream, lin_w, conv_w, Wt);
    hipLaunchKernelGGL(k_scales, dim3(12500), dim3(256), 0, stream,
                       node, h1, h2, h3, curv, scales);
    hipLaunchKernelGGL(k_hist, dim3(EBLK), dim3(256), 0, stream, edst, deg);
    hipLaunchKernelGGL(k_scan1, dim3(NBLK), dim3(256), 0, stream, deg, rowstart, blocksum);
    hipLaunchKernelGGL(k_scan2, dim3(1), dim3(256), 0, stream, blocksum);
    hipLaunchKernelGGL(k_bucket, dim3(EBLK), dim3(256), 0, stream,
                       esrc, edst, rowstart, blocksum, cursor, csr_src);
    hipLaunchKernelGGL(k_gather, dim3(12500), dim3(256), 0, stream,
                       csr_src, rowstart, blocksum, deg, node, scales, neigh);
    hipLaunchKernelGGL(k_gemm, dim3((N_NODES + RB - 1) / RB), dim3(256), 0, stream,
                       neigh, deg, scales, h1, h2, h3, Wt, lin_b, conv_b, curv, out);
}

// Round 7
// 276.205 us; speedup vs baseline: 2.9835x; 1.0715x over previous
//
#include <hip/hip_runtime.h>

#define N_NODES 50000
#define DIM 128
#define N_EDGES 625000
#define NBLK 196   // ceil(N/256) scan blocks
#define EBLK 2442  // ceil(E/256) edge blocks

// k_setup grid partition
#define SC_BLOCKS 12500           // scales+tangent: 16 rows/block over 4N rows
#define PK_BLOCKS 256             // W-pack: 65536 elems
#define ZR_BLOCKS 391             // zero deg+cursor: 100,000 ints
#define SETUP_BLOCKS (SC_BLOCKS + PK_BLOCKS + ZR_BLOCKS)

typedef float f32x4 __attribute__((ext_vector_type(4)));
typedef short s16x8 __attribute__((ext_vector_type(8)));

union U8 { unsigned short us[8]; uint4 v; };

__device__ __forceinline__ unsigned short f2bf(float f) {
    unsigned u = __builtin_bit_cast(unsigned, f);
    unsigned r = (u + 0x7fffu + ((u >> 16) & 1u)) >> 16;  // RNE
    return (unsigned short)r;
}
__device__ __forceinline__ float lo_bf(unsigned u) {
    return __builtin_bit_cast(float, u << 16);
}
__device__ __forceinline__ float hi_bf(unsigned u) {
    return __builtin_bit_cast(float, u & 0xffff0000u);
}

// ---- K1 fused setup ----
// blocks [0, SC_BLOCKS): logmap0 scales for [node,h1,h2,h3] -> scales[4N];
//                        for the node matrix also write node_t = bf16(tangent).
// blocks [SC, SC+PK): pack Wt[o][k] bf16 (k<128: lin_w[o][k]; else conv_w[o][i][kk]).
// blocks [SC+PK, ...): zero deg+cursor (adjacent 100,000 ints).
__global__ __launch_bounds__(256) void k_setup(
    const float* __restrict__ node, const float* __restrict__ h1,
    const float* __restrict__ h2, const float* __restrict__ h3,
    const float* __restrict__ lin_w, const float* __restrict__ conv_w,
    const float* __restrict__ curv,
    float* __restrict__ scales, unsigned short* __restrict__ node_t,
    unsigned short* __restrict__ Wt, int* __restrict__ zero_base) {
    int b = blockIdx.x;
    int tid = threadIdx.x;
    if (b < SC_BLOCKS) {
        int row = b * 16 + (tid >> 4);  // [0, 4N); a uniform per block (3125 | boundaries)
        int g = tid & 15;
        int a = row / N_NODES;
        int n = row - a * N_NODES;
        const float* src = (a == 0) ? node : (a == 1) ? h1 : (a == 2) ? h2 : h3;
        const float4* p = (const float4*)&src[n * DIM + g * 8];
        float4 x0 = p[0], x1 = p[1];
        float ss = x0.x * x0.x + x0.y * x0.y + x0.z * x0.z + x0.w * x0.w
                 + x1.x * x1.x + x1.y * x1.y + x1.z * x1.z + x1.w * x1.w;
        ss += __shfl_xor(ss, 1, 64);
        ss += __shfl_xor(ss, 2, 64);
        ss += __shfl_xor(ss, 4, 64);
        ss += __shfl_xor(ss, 8, 64);  // full 16-lane group reduction
        float c = fabsf(curv[0]);
        float sc = sqrtf(c);
        float xn = fmaxf(sqrtf(ss), 1e-15f);
        float arg = fminf(sc * xn, 1.0f - 1e-5f);
        float at = 0.5f * log1pf(2.0f * arg / (1.0f - arg));  // artanh
        float s = at / (sc * xn);
        if (g == 0) scales[row] = s;
        if (a == 0) {  // uniform per block
            U8 u;
            u.us[0] = f2bf(x0.x * s); u.us[1] = f2bf(x0.y * s);
            u.us[2] = f2bf(x0.z * s); u.us[3] = f2bf(x0.w * s);
            u.us[4] = f2bf(x1.x * s); u.us[5] = f2bf(x1.y * s);
            u.us[6] = f2bf(x1.z * s); u.us[7] = f2bf(x1.w * s);
            *(uint4*)&node_t[n * DIM + g * 8] = u.v;
        }
    } else if (b < SC_BLOCKS + PK_BLOCKS) {
        int idx = (b - SC_BLOCKS) * 256 + tid;  // 65536
        int o = idx >> 9;
        int k = idx & 511;
        float v;
        if (k < 128) {
            v = lin_w[o * 128 + k];
        } else {
            int kk = (k - 128) >> 7;
            int i = (k - 128) & 127;
            v = conv_w[o * 384 + i * 3 + kk];
        }
        Wt[idx] = f2bf(v);
    } else {
        int i = (b - SC_BLOCKS - PK_BLOCKS) * 256 + tid;
        if (i < 100000) zero_base[i] = 0;  // deg[50k] + cursor[50k], adjacent
    }
}

// ---- K2: degree histogram ----
__global__ void k_hist(const int* __restrict__ edst, int* __restrict__ deg) {
    int e = blockIdx.x * 256 + threadIdx.x;
    if (e < N_EDGES)
        __hip_atomic_fetch_add(&deg[edst[e]], 1, __ATOMIC_RELAXED, __HIP_MEMORY_SCOPE_AGENT);
}

// ---- K3a: per-256-chunk exclusive scan; chunk totals -> blocksum ----
__global__ void k_scan1(const int* __restrict__ deg, int* __restrict__ rowstart,
                        int* __restrict__ blocksum) {
    __shared__ int sm[256];
    int t = threadIdx.x;
    int i = blockIdx.x * 256 + t;
    int v = (i < N_NODES) ? deg[i] : 0;
    sm[t] = v;
    __syncthreads();
    #pragma unroll
    for (int off = 1; off < 256; off <<= 1) {
        int x = (t >= off) ? sm[t - off] : 0;
        __syncthreads();
        sm[t] += x;
        __syncthreads();
    }
    if (i < N_NODES) rowstart[i] = sm[t] - v;  // exclusive within chunk
    if (t == 255) blocksum[blockIdx.x] = sm[t];
}

// ---- K3b: exclusive scan of chunk totals (in place) ----
__global__ void k_scan2(int* __restrict__ blocksum) {
    __shared__ int sm[256];
    int t = threadIdx.x;
    int v = (t < NBLK) ? blocksum[t] : 0;
    sm[t] = v;
    __syncthreads();
    #pragma unroll
    for (int off = 1; off < 256; off <<= 1) {
        int x = (t >= off) ? sm[t - off] : 0;
        __syncthreads();
        sm[t] += x;
        __syncthreads();
    }
    if (t < NBLK) blocksum[t] = sm[t] - v;  // exclusive
}

// ---- K4: bucket edge sources by destination (CSR fill) ----
__global__ void k_bucket(const int* __restrict__ esrc, const int* __restrict__ edst,
                         const int* __restrict__ rowstart, const int* __restrict__ blocksum,
                         int* __restrict__ cursor, int* __restrict__ csr_src) {
    int e = blockIdx.x * 256 + threadIdx.x;
    if (e >= N_EDGES) return;
    int d = edst[e];
    int pos = __hip_atomic_fetch_add(&cursor[d], 1, __ATOMIC_RELAXED, __HIP_MEMORY_SCOPE_AGENT);
    csr_src[rowstart[d] + blocksum[d >> 8] + pos] = esrc[e];
}

// ---- K5: gather from bf16 tangent table: neigh[n] = bf16(avg of node_t rows) ----
// One wave per row; each lane covers 2 columns (4 B/row); 8 loads in flight.
__global__ __launch_bounds__(256) void k_gather(
    const int* __restrict__ csr_src, const int* __restrict__ rowstart,
    const int* __restrict__ blocksum, const int* __restrict__ deg,
    const unsigned short* __restrict__ node_t, unsigned short* __restrict__ neigh) {
    int n = blockIdx.x * 4 + (threadIdx.x >> 6);
    int lane = threadIdx.x & 63;
    int begin = rowstart[n] + blocksum[n >> 8];
    int cnt = deg[n];
    float a0 = 0.f, a1 = 0.f, b0 = 0.f, b1 = 0.f;
    float c0 = 0.f, c1 = 0.f, d0 = 0.f, d1 = 0.f;
    for (int base = 0; base < cnt; base += 64) {
        int rem = cnt - base;
        int m = rem < 64 ? rem : 64;
        int my = (lane < m) ? csr_src[begin + base + lane] : 0;
        int i = 0;
        for (; i + 8 <= m; i += 8) {
            int s0 = __shfl(my, i, 64),     s1 = __shfl(my, i + 1, 64);
            int s2 = __shfl(my, i + 2, 64), s3 = __shfl(my, i + 3, 64);
            int s4 = __shfl(my, i + 4, 64), s5 = __shfl(my, i + 5, 64);
            int s6 = __shfl(my, i + 6, 64), s7 = __shfl(my, i + 7, 64);
            unsigned u0 = *(const unsigned*)&node_t[s0 * DIM + lane * 2];
            unsigned u1 = *(const unsigned*)&node_t[s1 * DIM + lane * 2];
            unsigned u2 = *(const unsigned*)&node_t[s2 * DIM + lane * 2];
            unsigned u3 = *(const unsigned*)&node_t[s3 * DIM + lane * 2];
            unsigned u4 = *(const unsigned*)&node_t[s4 * DIM + lane * 2];
            unsigned u5 = *(const unsigned*)&node_t[s5 * DIM + lane * 2];
            unsigned u6 = *(const unsigned*)&node_t[s6 * DIM + lane * 2];
            unsigned u7 = *(const unsigned*)&node_t[s7 * DIM + lane * 2];
            a0 += lo_bf(u0); a1 += hi_bf(u0);
            b0 += lo_bf(u1); b1 += hi_bf(u1);
            c0 += lo_bf(u2); c1 += hi_bf(u2);
            d0 += lo_bf(u3); d1 += hi_bf(u3);
            a0 += lo_bf(u4); a1 += hi_bf(u4);
            b0 += lo_bf(u5); b1 += hi_bf(u5);
            c0 += lo_bf(u6); c1 += hi_bf(u6);
            d0 += lo_bf(u7); d1 += hi_bf(u7);
        }
        for (; i < m; ++i) {
            int s = __shfl(my, i, 64);
            unsigned u = *(const unsigned*)&node_t[s * DIM + lane * 2];
            a0 += lo_bf(u); a1 += hi_bf(u);
        }
    }
    float t0 = (a0 + b0) + (c0 + d0);
    float t1 = (a1 + b1) + (c1 + d1);
    float inv = (cnt > 0) ? 1.0f / (float)cnt : 0.0f;
    unsigned short o0 = f2bf(t0 * inv), o1 = f2bf(t1 * inv);
    *(unsigned*)&neigh[n * DIM + lane * 2] = (unsigned)o0 | ((unsigned)o1 << 16);
}

// ---- K6: [N x 512] @ [512 x 128] bf16 MFMA GEMM + expmap0 epilogue (f32 out) ----
#define RB 64
__global__ __launch_bounds__(256) void k_gemm(
    const unsigned short* __restrict__ neigh, const int* __restrict__ deg,
    const float* __restrict__ scales,  // [4][N]; rows 1..3 are hist scales
    const float* __restrict__ h1, const float* __restrict__ h2, const float* __restrict__ h3,
    const unsigned short* __restrict__ Wt,  // [128][512] bf16
    const float* __restrict__ lin_b, const float* __restrict__ conv_b,
    const float* __restrict__ curv, float* __restrict__ out) {
    __shared__ __align__(16) unsigned short As[RB * 136];
    __shared__ __align__(16) unsigned short Bs[128 * 136];
    int tid = threadIdx.x;
    int n0 = blockIdx.x * RB;
    int w = tid >> 6;
    int lane = tid & 63;
    int ml = lane & 15;
    int q = lane >> 4;

    f32x4 acc[8];
    #pragma unroll
    for (int i = 0; i < 8; ++i) acc[i] = (f32x4){0.f, 0.f, 0.f, 0.f};

    for (int kk = 0; kk < 4; ++kk) {
        #pragma unroll
        for (int it = 0; it < 8; ++it) {
            int cch = it * 256 + tid;  // 2048 chunks of 8 bf16
            int o = cch >> 4;
            int kc = (cch & 15) * 8;
            *(uint4*)&Bs[o * 136 + kc] = *(const uint4*)&Wt[o * 512 + kk * 128 + kc];
        }
        if (kk == 0) {
            #pragma unroll
            for (int it = 0; it < 4; ++it) {
                int cch = it * 256 + tid;  // 1024 chunks of 8
                int r = cch >> 4;
                int ic = (cch & 15) * 8;
                int n = n0 + r;
                U8 u;
                if (n < N_NODES) {
                    u.v = *(const uint4*)&neigh[n * DIM + ic];
                } else {
                    #pragma unroll
                    for (int j = 0; j < 8; ++j) u.us[j] = 0;
                }
                *(uint4*)&As[r * 136 + ic] = u.v;
            }
        } else {
            const float* hp = (kk == 1) ? h1 : (kk == 2) ? h2 : h3;
            const float* scl = scales + kk * N_NODES;
            #pragma unroll
            for (int it = 0; it < 4; ++it) {
                int cch = it * 256 + tid;
                int r = cch >> 4;
                int ic = (cch & 15) * 8;
                int n = n0 + r;
                U8 u;
                if (n < N_NODES) {
                    float s = scl[n];
                    const float4* fp = (const float4*)&hp[n * DIM + ic];
                    float4 f0 = fp[0], f1 = fp[1];
                    u.us[0] = f2bf(f0.x * s); u.us[1] = f2bf(f0.y * s);
                    u.us[2] = f2bf(f0.z * s); u.us[3] = f2bf(f0.w * s);
                    u.us[4] = f2bf(f1.x * s); u.us[5] = f2bf(f1.y * s);
                    u.us[6] = f2bf(f1.z * s); u.us[7] = f2bf(f1.w * s);
                } else {
                    #pragma unroll
                    for (int j = 0; j < 8; ++j) u.us[j] = 0;
                }
                *(uint4*)&As[r * 136 + ic] = u.v;
            }
        }
        __syncthreads();
        #pragma unroll
        for (int ks = 0; ks < 4; ++ks) {
            s16x8 a = *(const s16x8*)&As[(w * 16 + ml) * 136 + ks * 32 + q * 8];
            #pragma unroll
            for (int ct = 0; ct < 8; ++ct) {
                s16x8 b = *(const s16x8*)&Bs[(ct * 16 + ml) * 136 + ks * 32 + q * 8];
                acc[ct] = __builtin_amdgcn_mfma_f32_16x16x32_bf16(a, b, acc[ct], 0, 0, 0);
            }
        }
        __syncthreads();
    }

    float c = fabsf(curv[0]);
    float sc = sqrtf(c);
    float cb[8], lb[8];
    #pragma unroll
    for (int ct = 0; ct < 8; ++ct) {
        cb[ct] = conv_b[ct * 16 + ml];
        lb[ct] = lin_b[ct * 16 + ml];
    }
    #pragma unroll
    for (int r = 0; r < 4; ++r) {
        int n = n0 + w * 16 + q * 4 + r;  // D-frag: row = quad*4 + reg, col = lane&15
        bool valid = (n < N_NODES);
        float dgf = 0.f;
        if (valid) dgf = (deg[n] > 0) ? 1.0f : 0.0f;
        float y[8];
        float ssq = 0.f;
        #pragma unroll
        for (int ct = 0; ct < 8; ++ct) {
            float v = acc[ct][r] + cb[ct] + dgf * lb[ct];
            y[ct] = v;
            ssq += v * v;
        }
        ssq += __shfl_xor(ssq, 1, 64);
        ssq += __shfl_xor(ssq, 2, 64);
        ssq += __shfl_xor(ssq, 4, 64);
        ssq += __shfl_xor(ssq, 8, 64);
        float un = fmaxf(sqrtf(ssq), 1e-15f);
        float os = tanhf(sc * un) / (sc * un);
        if (valid) {
            #pragma unroll
            for (int ct = 0; ct < 8; ++ct)
                out[n * DIM + ct * 16 + ml] = y[ct] * os;  // f32 output
        }
    }
}

extern "C" void kernel_launch(void* const* d_in, const int* in_sizes, int n_in,
                              void* d_out, int out_size, void* d_ws, size_t ws_size,
                              hipStream_t stream) {
    (void)in_sizes; (void)n_in; (void)out_size; (void)ws_size;
    const float* node   = (const float*)d_in[0];   // inputs f32, output f32 (confirmed R3)
    const float* h1     = (const float*)d_in[1];
    const float* h2     = (const float*)d_in[2];
    const float* h3     = (const float*)d_in[3];
    const float* lin_w  = (const float*)d_in[4];
    const float* lin_b  = (const float*)d_in[5];
    const float* conv_w = (const float*)d_in[6];
    const float* conv_b = (const float*)d_in[7];
    const float* curv   = (const float*)d_in[8];
    const int* esrc = (const int*)d_in[9];
    const int* edst = (const int*)d_in[10];
    float* out = (float*)d_out;

    // ws layout (bytes):
    //   [0, 12,800,000)           neigh    bf16 [N][128]
    //   [12,800,000, 25,600,000)  node_t   bf16 [N][128] (pre-scaled tangent)
    //   [25,600,000, 26,400,000)  scales   f32  [4][N]
    //   [26,400,000, 26,531,072)  Wt       bf16 [128][512]
    //   [26,531,072, 26,731,072)  deg      i32  [N]   } adjacent for fused zero
    //   [26,731,072, 26,931,072)  cursor   i32  [N]   }
    //   [26,931,072, 27,131,072)  rowstart i32  [N]
    //   [27,131,072, 29,631,072)  csr_src  i32  [E]
    //   [29,631,072, 29,632,096)  blocksum i32  [256]
    char* ws = (char*)d_ws;
    unsigned short* neigh = (unsigned short*)ws;
    unsigned short* node_t = (unsigned short*)(ws + 12800000);
    float* scales = (float*)(ws + 25600000);
    unsigned short* Wt = (unsigned short*)(ws + 26400000);
    int* deg = (int*)(ws + 26531072);
    int* cursor = (int*)(ws + 26731072);
    int* rowstart = (int*)(ws + 26931072);
    int* csr_src = (int*)(ws + 27131072);
    int* blocksum = (int*)(ws + 29631072);

    hipLaunchKernelGGL(k_setup, dim3(SETUP_BLOCKS), dim3(256), 0, stream,
                       node, h1, h2, h3, lin_w, conv_w, curv, scales, node_t, Wt, deg);
    hipLaunchKernelGGL(k_hist, dim3(EBLK), dim3(256), 0, stream, edst, deg);
    hipLaunchKernelGGL(k_scan1, dim3(NBLK), dim3(256), 0, stream, deg, rowstart, blocksum);
    hipLaunchKernelGGL(k_scan2, dim3(1), dim3(256), 0, stream, blocksum);
    hipLaunchKernelGGL(k_bucket, dim3(EBLK), dim3(256), 0, stream,
                       esrc, edst, rowstart, blocksum, cursor, csr_src);
    hipLaunchKernelGGL(k_gather, dim3(12500), dim3(256), 0, stream,
                       csr_src, rowstart, blocksum, deg, node_t, neigh);
    hipLaunchKernelGGL(k_gemm, dim3((N_NODES + RB - 1) / RB), dim3(256), 0, stream,
                       neigh, deg, scales, h1, h2, h3, Wt, lin_b, conv_b, curv, out);
}

// Round 8
// 269.913 us; speedup vs baseline: 3.0531x; 1.0233x over previous
//
#include <hip/hip_runtime.h>

#define N_NODES 50000
#define DIM 128
#define N_EDGES 625000
#define NBLK 196   // ceil(N/256) scan blocks
#define EBLK 2442  // ceil(E/256) edge blocks

// k_setup grid partition
#define SC_BLOCKS 12500           // scales/tangents: 16 rows/block over 4N rows
#define PK_BLOCKS 256             // W-pack: 65536 elems
#define ZR_BLOCKS 391             // zero deg+cursor: 100,000 ints
#define SETUP_BLOCKS (SC_BLOCKS + PK_BLOCKS + ZR_BLOCKS)

typedef float f32x4 __attribute__((ext_vector_type(4)));
typedef short s16x8 __attribute__((ext_vector_type(8)));

union U8 { unsigned short us[8]; uint4 v; };

__device__ __forceinline__ unsigned short f2bf(float f) {
    unsigned u = __builtin_bit_cast(unsigned, f);
    unsigned r = (u + 0x7fffu + ((u >> 16) & 1u)) >> 16;  // RNE
    return (unsigned short)r;
}
__device__ __forceinline__ float lo_bf(unsigned u) {
    return __builtin_bit_cast(float, u << 16);
}
__device__ __forceinline__ float hi_bf(unsigned u) {
    return __builtin_bit_cast(float, u & 0xffff0000u);
}

// async global->LDS, 16 B per lane; lds dest = uniform base + lane*16 (m104)
__device__ __forceinline__ void gload_lds16(const unsigned short* g, unsigned short* l) {
    __builtin_amdgcn_global_load_lds(
        (const __attribute__((address_space(1))) void*)g,
        (__attribute__((address_space(3))) void*)l, 16, 0, 0);
}

// ---- K1 fused setup ----
// blocks [0, SC): logmap0 per-row scale; a==0 -> node_t = bf16(scale*node);
//                 a>0 -> A[n][a*128..] = bf16(scale*h_a)  (pre-packed GEMM A cols)
// blocks [SC, SC+PK): pack Wt[o][k] bf16 (k<128: lin_w[o][k]; else conv_w[o][i][kk])
// blocks [SC+PK, ...): zero deg+cursor
__global__ __launch_bounds__(256) void k_setup(
    const float* __restrict__ node, const float* __restrict__ h1,
    const float* __restrict__ h2, const float* __restrict__ h3,
    const float* __restrict__ lin_w, const float* __restrict__ conv_w,
    const float* __restrict__ curv,
    unsigned short* __restrict__ node_t, unsigned short* __restrict__ A,
    unsigned short* __restrict__ Wt, int* __restrict__ zero_base) {
    int b = blockIdx.x;
    int tid = threadIdx.x;
    if (b < SC_BLOCKS) {
        int row = b * 16 + (tid >> 4);  // [0, 4N); matrix index uniform per block
        int g = tid & 15;
        int a = row / N_NODES;
        int n = row - a * N_NODES;
        const float* src = (a == 0) ? node : (a == 1) ? h1 : (a == 2) ? h2 : h3;
        const float4* p = (const float4*)&src[n * DIM + g * 8];
        float4 x0 = p[0], x1 = p[1];
        float ss = x0.x * x0.x + x0.y * x0.y + x0.z * x0.z + x0.w * x0.w
                 + x1.x * x1.x + x1.y * x1.y + x1.z * x1.z + x1.w * x1.w;
        ss += __shfl_xor(ss, 1, 64);
        ss += __shfl_xor(ss, 2, 64);
        ss += __shfl_xor(ss, 4, 64);
        ss += __shfl_xor(ss, 8, 64);  // 16-lane group reduction
        float c = fabsf(curv[0]);
        float sc = sqrtf(c);
        float xn = fmaxf(sqrtf(ss), 1e-15f);
        float arg = fminf(sc * xn, 1.0f - 1e-5f);
        float at = 0.5f * log1pf(2.0f * arg / (1.0f - arg));  // artanh
        float s = at / (sc * xn);
        U8 u;
        u.us[0] = f2bf(x0.x * s); u.us[1] = f2bf(x0.y * s);
        u.us[2] = f2bf(x0.z * s); u.us[3] = f2bf(x0.w * s);
        u.us[4] = f2bf(x1.x * s); u.us[5] = f2bf(x1.y * s);
        u.us[6] = f2bf(x1.z * s); u.us[7] = f2bf(x1.w * s);
        if (a == 0) {  // branch uniform per block
            *(uint4*)&node_t[n * DIM + g * 8] = u.v;
        } else {
            *(uint4*)&A[n * 512 + a * 128 + g * 8] = u.v;
        }
    } else if (b < SC_BLOCKS + PK_BLOCKS) {
        int idx = (b - SC_BLOCKS) * 256 + tid;  // 65536
        int o = idx >> 9;
        int k = idx & 511;
        float v;
        if (k < 128) {
            v = lin_w[o * 128 + k];
        } else {
            int kk = (k - 128) >> 7;
            int i = (k - 128) & 127;
            v = conv_w[o * 384 + i * 3 + kk];
        }
        Wt[idx] = f2bf(v);
    } else {
        int i = (b - SC_BLOCKS - PK_BLOCKS) * 256 + tid;
        if (i < 100000) zero_base[i] = 0;  // deg[50k] + cursor[50k], adjacent
    }
}

// ---- K2: degree histogram ----
__global__ void k_hist(const int* __restrict__ edst, int* __restrict__ deg) {
    int e = blockIdx.x * 256 + threadIdx.x;
    if (e < N_EDGES)
        __hip_atomic_fetch_add(&deg[edst[e]], 1, __ATOMIC_RELAXED, __HIP_MEMORY_SCOPE_AGENT);
}

// ---- K3a: per-256-chunk exclusive scan; chunk totals -> blocksum ----
__global__ void k_scan1(const int* __restrict__ deg, int* __restrict__ rowstart,
                        int* __restrict__ blocksum) {
    __shared__ int sm[256];
    int t = threadIdx.x;
    int i = blockIdx.x * 256 + t;
    int v = (i < N_NODES) ? deg[i] : 0;
    sm[t] = v;
    __syncthreads();
    #pragma unroll
    for (int off = 1; off < 256; off <<= 1) {
        int x = (t >= off) ? sm[t - off] : 0;
        __syncthreads();
        sm[t] += x;
        __syncthreads();
    }
    if (i < N_NODES) rowstart[i] = sm[t] - v;  // exclusive within chunk
    if (t == 255) blocksum[blockIdx.x] = sm[t];
}

// ---- K3b: exclusive scan of chunk totals (in place) ----
__global__ void k_scan2(int* __restrict__ blocksum) {
    __shared__ int sm[256];
    int t = threadIdx.x;
    int v = (t < NBLK) ? blocksum[t] : 0;
    sm[t] = v;
    __syncthreads();
    #pragma unroll
    for (int off = 1; off < 256; off <<= 1) {
        int x = (t >= off) ? sm[t - off] : 0;
        __syncthreads();
        sm[t] += x;
        __syncthreads();
    }
    if (t < NBLK) blocksum[t] = sm[t] - v;  // exclusive
}

// ---- K4: bucket edge sources by destination (CSR fill) ----
__global__ void k_bucket(const int* __restrict__ esrc, const int* __restrict__ edst,
                         const int* __restrict__ rowstart, const int* __restrict__ blocksum,
                         int* __restrict__ cursor, int* __restrict__ csr_src) {
    int e = blockIdx.x * 256 + threadIdx.x;
    if (e >= N_EDGES) return;
    int d = edst[e];
    int pos = __hip_atomic_fetch_add(&cursor[d], 1, __ATOMIC_RELAXED, __HIP_MEMORY_SCOPE_AGENT);
    csr_src[rowstart[d] + blocksum[d >> 8] + pos] = esrc[e];
}

// ---- K5: gather: A[n][0:128] = bf16(avg of node_t rows in CSR row n) ----
__global__ __launch_bounds__(256) void k_gather(
    const int* __restrict__ csr_src, const int* __restrict__ rowstart,
    const int* __restrict__ blocksum, const int* __restrict__ deg,
    const unsigned short* __restrict__ node_t, unsigned short* __restrict__ A) {
    int n = blockIdx.x * 4 + (threadIdx.x >> 6);
    int lane = threadIdx.x & 63;
    int begin = rowstart[n] + blocksum[n >> 8];
    int cnt = deg[n];
    float a0 = 0.f, a1 = 0.f, b0 = 0.f, b1 = 0.f;
    float c0 = 0.f, c1 = 0.f, d0 = 0.f, d1 = 0.f;
    for (int base = 0; base < cnt; base += 64) {
        int rem = cnt - base;
        int m = rem < 64 ? rem : 64;
        int my = (lane < m) ? csr_src[begin + base + lane] : 0;
        int i = 0;
        for (; i + 8 <= m; i += 8) {
            int s0 = __shfl(my, i, 64),     s1 = __shfl(my, i + 1, 64);
            int s2 = __shfl(my, i + 2, 64), s3 = __shfl(my, i + 3, 64);
            int s4 = __shfl(my, i + 4, 64), s5 = __shfl(my, i + 5, 64);
            int s6 = __shfl(my, i + 6, 64), s7 = __shfl(my, i + 7, 64);
            unsigned u0 = *(const unsigned*)&node_t[s0 * DIM + lane * 2];
            unsigned u1 = *(const unsigned*)&node_t[s1 * DIM + lane * 2];
            unsigned u2 = *(const unsigned*)&node_t[s2 * DIM + lane * 2];
            unsigned u3 = *(const unsigned*)&node_t[s3 * DIM + lane * 2];
            unsigned u4 = *(const unsigned*)&node_t[s4 * DIM + lane * 2];
            unsigned u5 = *(const unsigned*)&node_t[s5 * DIM + lane * 2];
            unsigned u6 = *(const unsigned*)&node_t[s6 * DIM + lane * 2];
            unsigned u7 = *(const unsigned*)&node_t[s7 * DIM + lane * 2];
            a0 += lo_bf(u0); a1 += hi_bf(u0);
            b0 += lo_bf(u1); b1 += hi_bf(u1);
            c0 += lo_bf(u2); c1 += hi_bf(u2);
            d0 += lo_bf(u3); d1 += hi_bf(u3);
            a0 += lo_bf(u4); a1 += hi_bf(u4);
            b0 += lo_bf(u5); b1 += hi_bf(u5);
            c0 += lo_bf(u6); c1 += hi_bf(u6);
            d0 += lo_bf(u7); d1 += hi_bf(u7);
        }
        for (; i < m; ++i) {
            int s = __shfl(my, i, 64);
            unsigned u = *(const unsigned*)&node_t[s * DIM + lane * 2];
            a0 += lo_bf(u); a1 += hi_bf(u);
        }
    }
    float t0 = (a0 + b0) + (c0 + d0);
    float t1 = (a1 + b1) + (c1 + d1);
    float inv = (cnt > 0) ? 1.0f / (float)cnt : 0.0f;
    unsigned short o0 = f2bf(t0 * inv), o1 = f2bf(t1 * inv);
    *(unsigned*)&A[n * 512 + lane * 2] = (unsigned)o0 | ((unsigned)o1 << 16);
}

// ---- K6: [N x 512] @ [512 x 128] bf16 MFMA GEMM + expmap0 epilogue (f32 out) ----
// A pre-packed bf16 [50048][512]; staged via global_load_lds with XOR swizzle:
// 16-B chunk j of row r lives at LDS slot j^(r&7) -> MFMA reads are 2-way max.
#define RB 64
__global__ __launch_bounds__(256) void k_gemm(
    const unsigned short* __restrict__ A, const int* __restrict__ deg,
    const unsigned short* __restrict__ Wt,  // [128][512] bf16
    const float* __restrict__ lin_b, const float* __restrict__ conv_b,
    const float* __restrict__ curv, float* __restrict__ out) {
    __shared__ __align__(16) unsigned short As[RB * 128];    // 16 KB / chunk
    __shared__ __align__(16) unsigned short Bs[128 * 128];   // 32 KB / chunk
    int tid = threadIdx.x;
    int n0 = blockIdx.x * RB;
    int w = tid >> 6;
    int lane = tid & 63;
    int ml = lane & 15;
    int q = lane >> 4;
    int lr = lane >> 4;      // row-within-4 for staging
    int lj = lane & 15;      // chunk-within-row for staging

    f32x4 acc[8];
    #pragma unroll
    for (int i = 0; i < 8; ++i) acc[i] = (f32x4){0.f, 0.f, 0.f, 0.f};

    for (int kk = 0; kk < 4; ++kk) {
        // stage A chunk: 64 rows x 128 ushorts = 16 chunks of 1 KB (4 rows each)
        #pragma unroll
        for (int t = 0; t < 4; ++t) {
            int m = t * 4 + w;
            int r = m * 4 + lr;
            int jg = lj ^ (r & 7);
            gload_lds16(A + (n0 + r) * 512 + kk * 128 + jg * 8, &As[m * 512]);
        }
        // stage B chunk: 128 rows x 128 ushorts = 32 chunks of 1 KB
        #pragma unroll
        for (int t = 0; t < 8; ++t) {
            int m = t * 4 + w;
            int o = m * 4 + lr;
            int jg = lj ^ (o & 7);
            gload_lds16(Wt + o * 512 + kk * 128 + jg * 8, &Bs[m * 512]);
        }
        __syncthreads();
        #pragma unroll
        for (int ks = 0; ks < 4; ++ks) {
            int swz = ((ks * 4 + q) ^ (ml & 7)) * 8;
            s16x8 a = *(const s16x8*)&As[(w * 16 + ml) * 128 + swz];
            #pragma unroll
            for (int ct = 0; ct < 8; ++ct) {
                s16x8 b = *(const s16x8*)&Bs[(ct * 16 + ml) * 128 + swz];
                acc[ct] = __builtin_amdgcn_mfma_f32_16x16x32_bf16(a, b, acc[ct], 0, 0, 0);
            }
        }
        __syncthreads();
    }

    float c = fabsf(curv[0]);
    float sc = sqrtf(c);
    float cb[8], lb[8];
    #pragma unroll
    for (int ct = 0; ct < 8; ++ct) {
        cb[ct] = conv_b[ct * 16 + ml];
        lb[ct] = lin_b[ct * 16 + ml];
    }
    #pragma unroll
    for (int r = 0; r < 4; ++r) {
        int n = n0 + w * 16 + q * 4 + r;  // D-frag: row = quad*4 + reg, col = lane&15
        bool valid = (n < N_NODES);
        float dgf = 0.f;
        if (valid) dgf = (deg[n] > 0) ? 1.0f : 0.0f;
        float y[8];
        float ssq = 0.f;
        #pragma unroll
        for (int ct = 0; ct < 8; ++ct) {
            float v = acc[ct][r] + cb[ct] + dgf * lb[ct];
            y[ct] = v;
            ssq += v * v;
        }
        ssq += __shfl_xor(ssq, 1, 64);
        ssq += __shfl_xor(ssq, 2, 64);
        ssq += __shfl_xor(ssq, 4, 64);
        ssq += __shfl_xor(ssq, 8, 64);
        float un = fmaxf(sqrtf(ssq), 1e-15f);
        float os = tanhf(sc * un) / (sc * un);
        if (valid) {
            #pragma unroll
            for (int ct = 0; ct < 8; ++ct)
                out[n * DIM + ct * 16 + ml] = y[ct] * os;  // f32 output
        }
    }
}

extern "C" void kernel_launch(void* const* d_in, const int* in_sizes, int n_in,
                              void* d_out, int out_size, void* d_ws, size_t ws_size,
                              hipStream_t stream) {
    (void)in_sizes; (void)n_in; (void)out_size; (void)ws_size;
    const float* node   = (const float*)d_in[0];   // inputs f32, output f32 (confirmed R3)
    const float* h1     = (const float*)d_in[1];
    const float* h2     = (const float*)d_in[2];
    const float* h3     = (const float*)d_in[3];
    const float* lin_w  = (const float*)d_in[4];
    const float* lin_b  = (const float*)d_in[5];
    const float* conv_w = (const float*)d_in[6];
    const float* conv_b = (const float*)d_in[7];
    const float* curv   = (const float*)d_in[8];
    const int* esrc = (const int*)d_in[9];
    const int* edst = (const int*)d_in[10];
    float* out = (float*)d_out;

    // ws layout (bytes):
    //   [0, 51,249,152)           A        bf16 [50048][512] (0:128 neigh | h1t | h2t | h3t)
    //   [51,249,152, 64,049,152)  node_t   bf16 [N][128] (pre-scaled node tangent)
    //   [64,049,152, 64,180,224)  Wt       bf16 [128][512]
    //   [64,180,224, 64,380,224)  deg      i32 [N]   } adjacent for fused zero
    //   [64,380,224, 64,580,224)  cursor   i32 [N]   }
    //   [64,580,224, 64,780,224)  rowstart i32 [N]
    //   [64,780,224, 67,280,224)  csr_src  i32 [E]
    //   [67,280,224, 67,281,248)  blocksum i32 [256]
    char* ws = (char*)d_ws;
    unsigned short* A = (unsigned short*)ws;
    unsigned short* node_t = (unsigned short*)(ws + 51249152);
    unsigned short* Wt = (unsigned short*)(ws + 64049152);
    int* deg = (int*)(ws + 64180224);
    int* cursor = (int*)(ws + 64380224);
    int* rowstart = (int*)(ws + 64580224);
    int* csr_src = (int*)(ws + 64780224);
    int* blocksum = (int*)(ws + 67280224);

    hipLaunchKernelGGL(k_setup, dim3(SETUP_BLOCKS), dim3(256), 0, stream,
                       node, h1, h2, h3, lin_w, conv_w, curv, node_t, A, Wt, deg);
    hipLaunchKernelGGL(k_hist, dim3(EBLK), dim3(256), 0, stream, edst, deg);
    hipLaunchKernelGGL(k_scan1, dim3(NBLK), dim3(256), 0, stream, deg, rowstart, blocksum);
    hipLaunchKernelGGL(k_scan2, dim3(1), dim3(256), 0, stream, blocksum);
    hipLaunchKernelGGL(k_bucket, dim3(EBLK), dim3(256), 0, stream,
                       esrc, edst, rowstart, blocksum, cursor, csr_src);
    hipLaunchKernelGGL(k_gather, dim3(12500), dim3(256), 0, stream,
                       csr_src, rowstart, blocksum, deg, node_t, A);
    hipLaunchKernelGGL(k_gemm, dim3((N_NODES + RB - 1) / RB), dim3(256), 0, stream,
                       A, deg, Wt, lin_b, conv_b, curv, out);
}